// Round 1
// baseline (953.050 us; speedup 1.0000x reference)
//
#include <hip/hip_runtime.h>

// LSTM (B=4096, T=512, IN=4, H=50) + final FC on h_T.
// One wave per batch element; lane l<50 owns hidden unit l and computes
// gate rows l, 50+l, 100+l, 150+l. W_hh rows held in registers (~200 VGPR);
// h broadcast per step via a 64-float LDS buffer read with uniform float4
// loads (LDS broadcast = conflict-free).

#define HID 50
#define NIN 4
#define TT  512

__device__ __forceinline__ float fast_sigmoid(float v) {
    // 1/(1+exp(-v)) = rcp(1 + exp2(-v*log2e))
    float e = __builtin_amdgcn_exp2f(v * -1.442695040888963f);
    return __builtin_amdgcn_rcpf(1.0f + e);
}
__device__ __forceinline__ float fast_tanh(float v) {
    // tanh(v) = 2*sigmoid(2v) - 1
    float e = __builtin_amdgcn_exp2f(v * -2.885390081777927f);
    return 2.0f * __builtin_amdgcn_rcpf(1.0f + e) - 1.0f;
}

__global__ __launch_bounds__(64, 2)
void lstm_fused(const float* __restrict__ x,     // [B,T,4]
                const float* __restrict__ W_ih,  // [200,4]
                const float* __restrict__ W_hh,  // [200,50]
                const float* __restrict__ b_ih,  // [200]
                const float* __restrict__ b_hh,  // [200]
                const float* __restrict__ W_fc,  // [1,50]
                const float* __restrict__ b_fc,  // [1]
                float* __restrict__ out)         // [B,1]
{
    __shared__ float hsh[64];
    const int b    = blockIdx.x;
    const int lane = threadIdx.x;          // 0..63, lanes >= 50 are padding
    const bool act = lane < HID;

    // ---- per-lane weights in registers (all indices compile-time) ----
    float w[4][HID];     // W_hh rows for this lane's 4 gates
    float wi[4][NIN];    // W_ih rows
    float bias[4];       // b_ih + b_hh folded
#pragma unroll
    for (int g = 0; g < 4; ++g) {
        const int row = g * HID + lane;
#pragma unroll
        for (int k = 0; k < HID; ++k)
            w[g][k] = act ? W_hh[row * HID + k] : 0.0f;
#pragma unroll
        for (int d = 0; d < NIN; ++d)
            wi[g][d] = act ? W_ih[row * NIN + d] : 0.0f;
        bias[g] = act ? (b_ih[row] + b_hh[row]) : 0.0f;
    }
    const float wfc = act ? W_fc[lane] : 0.0f;

    const float* xb = x + (size_t)b * TT * NIN;
    float4 xv = *(const float4*)xb;        // x[b][0][:]
    float h = 0.0f, c = 0.0f;
    hsh[lane] = 0.0f;
    __syncthreads();

    for (int t = 0; t < TT; ++t) {
        // prefetch next timestep's x (hide global latency under the FMAs)
        float4 xn = xv;
        if (t + 1 < TT) xn = *(const float4*)(xb + (size_t)(t + 1) * NIN);

        float a[4];
#pragma unroll
        for (int g = 0; g < 4; ++g)
            a[g] = bias[g] + wi[g][0] * xv.x + wi[g][1] * xv.y
                           + wi[g][2] * xv.z + wi[g][3] * xv.w;

        // h @ W_hh^T : broadcast h 4-at-a-time from LDS (uniform address)
#pragma unroll
        for (int kk = 0; kk < 12; ++kk) {
            const float4 hv = *(const float4*)&hsh[kk * 4];
#pragma unroll
            for (int g = 0; g < 4; ++g) {
                a[g] += w[g][4 * kk + 0] * hv.x;
                a[g] += w[g][4 * kk + 1] * hv.y;
                a[g] += w[g][4 * kk + 2] * hv.z;
                a[g] += w[g][4 * kk + 3] * hv.w;
            }
        }
        {   // tail k = 48,49
            const float2 hv = *(const float2*)&hsh[48];
#pragma unroll
            for (int g = 0; g < 4; ++g) {
                a[g] += w[g][48] * hv.x;
                a[g] += w[g][49] * hv.y;
            }
        }

        const float gi = fast_sigmoid(a[0]);
        const float gf = fast_sigmoid(a[1]);
        const float gg = fast_tanh(a[2]);
        const float go = fast_sigmoid(a[3]);
        c = gf * c + gi * gg;
        h = go * fast_tanh(c);

        __syncthreads();          // all reads of old h done (single-wave: cheap)
        hsh[lane] = h;            // lanes >= 50 write h == 0 (harmless padding)
        __syncthreads();          // new h visible
        xv = xn;
    }

    // out[b] = h_T . W_fc + b_fc  (wave-wide reduction, inactive lanes add 0)
    float v = h * wfc;
#pragma unroll
    for (int off = 32; off > 0; off >>= 1)
        v += __shfl_down(v, off);
    if (lane == 0) out[b] = v + b_fc[0];
}

extern "C" void kernel_launch(void* const* d_in, const int* in_sizes, int n_in,
                              void* d_out, int out_size, void* d_ws, size_t ws_size,
                              hipStream_t stream) {
    const float* x    = (const float*)d_in[0];
    const float* W_ih = (const float*)d_in[1];
    const float* W_hh = (const float*)d_in[2];
    const float* b_ih = (const float*)d_in[3];
    const float* b_hh = (const float*)d_in[4];
    const float* W_fc = (const float*)d_in[5];
    const float* b_fc = (const float*)d_in[6];
    float* out        = (float*)d_out;

    const int B = in_sizes[0] / (TT * NIN);   // 4096
    lstm_fused<<<B, 64, 0, stream>>>(x, W_ih, W_hh, b_ih, b_hh, W_fc, b_fc, out);
}

// Round 2
// 300.772 us; speedup vs baseline: 3.1687x; 3.1687x over previous
//
#include <hip/hip_runtime.h>

// LSTM (B=4096, T=512, IN=4, H=50) + final FC, MFMA formulation.
// Per step, per 16-batch tile: gates[200x16] = Wcat[200x64] @ [h;x][64x16]
// via mfma_f32_16x16x32_bf16. Weight rows interleaved row' = 4u+g so each
// lane's 4 C-regs are (i,f,g,o) of one hidden unit. Weights preloaded as
// A-fragments in VGPRs; [h;x] staged bf16 in double-buffered LDS, one
// barrier per step. c/h/activations stay fp32.

#define HID  50
#define NROW 200          // 4*HID
#define TT   512
#define NIN  4
#define BT   16           // batch tile
#define KD   72           // LDS row width (bf16): k 0..49 h, 56..59 x, rest 0
#define XOFF 56
#define NW   8            // waves per block

typedef float f32x4 __attribute__((ext_vector_type(4)));
typedef short s16x8 __attribute__((ext_vector_type(8)));

__device__ __forceinline__ unsigned short f2bf(float f) {
    unsigned u = __builtin_bit_cast(unsigned, f);
    return (unsigned short)((u + 0x7FFF + ((u >> 16) & 1)) >> 16);
}
__device__ __forceinline__ float fast_sigmoid(float v) {
    float e = __builtin_amdgcn_exp2f(v * -1.442695040888963f);
    return __builtin_amdgcn_rcpf(1.0f + e);
}
__device__ __forceinline__ float fast_tanh(float v) {
    float e = __builtin_amdgcn_exp2f(v * -2.885390081777927f);
    return 2.0f * __builtin_amdgcn_rcpf(1.0f + e) - 1.0f;
}

__global__ __launch_bounds__(64 * NW, 2)
void lstm_mfma(const float* __restrict__ x,     // [B,T,4]
               const float* __restrict__ W_ih,  // [200,4]
               const float* __restrict__ W_hh,  // [200,50]
               const float* __restrict__ b_ih,  // [200]
               const float* __restrict__ b_hh,  // [200]
               const float* __restrict__ W_fc,  // [1,50]
               const float* __restrict__ b_fc,  // [1]
               float* __restrict__ out)         // [B,1]
{
    __shared__ __align__(16) unsigned short buf[2][BT][KD]; // bf16 bits
    __shared__ float red[BT];

    const int tid = threadIdx.x;
    const int w   = tid >> 6;        // wave 0..7
    const int l   = tid & 63;
    const int lr  = l & 15;          // A: row-in-tile; B/D: batch col
    const int lg  = l >> 4;          // k-group / D row-group
    const int b0  = blockIdx.x * BT;

    // ---- zero LDS staging (pad k-slots MUST be 0: 0*garbage/NaN hazard) ----
    for (int i = tid; i < 2 * BT * KD; i += 64 * NW)
        ((unsigned short*)buf)[i] = 0;
    if (tid < BT) red[tid] = 0.0f;

    // ---- preload A fragments (weights), bias, W_fc ----
    // wave w owns m-tiles T = w and w+8 (tiles 13..15 are zero padding)
    s16x8 afrag[2][2];   // [tile][k-half]
    f32x4 bias[2];
    float wfc[2];
#pragma unroll
    for (int ti = 0; ti < 2; ++ti) {
        const int T   = w + 8 * ti;
        const int row = 16 * T + lr;             // row' = 4u+g
        const int u   = row >> 2, g = row & 3;
        const bool real = row < NROW;
#pragma unroll
        for (int kh = 0; kh < 2; ++kh) {
            s16x8 f;
#pragma unroll
            for (int j = 0; j < 8; ++j) {
                const int k = 32 * kh + 8 * lg + j;
                float v = 0.0f;
                if (real) {
                    if (k < HID)                        v = W_hh[(g * HID + u) * HID + k];
                    else if (k >= XOFF && k < XOFF+NIN) v = W_ih[(g * HID + u) * NIN + (k - XOFF)];
                }
                f[j] = (short)f2bf(v);
            }
            afrag[ti][kh] = f;
        }
        f32x4 bv;
#pragma unroll
        for (int r = 0; r < 4; ++r) {
            const int rr = 16 * T + 4 * lg + r;  // D row for acc reg r
            bv[r] = (rr < NROW) ? (b_ih[(rr & 3) * HID + (rr >> 2)] +
                                   b_hh[(rr & 3) * HID + (rr >> 2)]) : 0.0f;
        }
        bias[ti] = bv;
        const int uu = 4 * T + lg;
        wfc[ti] = (uu < HID) ? W_fc[uu] : 0.0f;
    }

    // wave 7 owns x staging; preload x[0] into buf[0]
    const float* xb = x + (size_t)(b0 + lr) * TT * NIN;
    if (w == 7 && l < 16) {
        const float4 xv = *(const float4*)xb;
        uint2 pk;
        pk.x = (unsigned)f2bf(xv.x) | ((unsigned)f2bf(xv.y) << 16);
        pk.y = (unsigned)f2bf(xv.z) | ((unsigned)f2bf(xv.w) << 16);
        *(uint2*)&buf[0][lr][XOFF] = pk;
    }
    __syncthreads();

    float c[2]  = {0.0f, 0.0f};
    float hr[2] = {0.0f, 0.0f};

    for (int t = 0; t < TT; ++t) {
        const int p = t & 1;

        // wave 7: fetch x[t+1] early (latency hides under MFMAs+activations)
        float4 xv;
        const bool xduty = (w == 7) && (l < 16) && (t + 1 < TT);
        if (xduty) xv = *(const float4*)(xb + (size_t)(t + 1) * NIN);

        // B fragments: [h;x] columns for all 16 batches
        const s16x8 bf0 = *(const s16x8*)&buf[p][lr][8 * lg];
        const s16x8 bf1 = *(const s16x8*)&buf[p][lr][32 + 8 * lg];

        f32x4 acc0 = bias[0], acc1 = bias[1];
        acc0 = __builtin_amdgcn_mfma_f32_16x16x32_bf16(afrag[0][0], bf0, acc0, 0, 0, 0);
        acc0 = __builtin_amdgcn_mfma_f32_16x16x32_bf16(afrag[0][1], bf1, acc0, 0, 0, 0);
        acc1 = __builtin_amdgcn_mfma_f32_16x16x32_bf16(afrag[1][0], bf0, acc1, 0, 0, 0);
        acc1 = __builtin_amdgcn_mfma_f32_16x16x32_bf16(afrag[1][1], bf1, acc1, 0, 0, 0);

        if (xduty) {
            uint2 pk;
            pk.x = (unsigned)f2bf(xv.x) | ((unsigned)f2bf(xv.y) << 16);
            pk.y = (unsigned)f2bf(xv.z) | ((unsigned)f2bf(xv.w) << 16);
            *(uint2*)&buf[p ^ 1][lr][XOFF] = pk;
        }

        // activations: lane holds (i,f,g,o) of unit u = 4T+lg, batch lr
#pragma unroll
        for (int ti = 0; ti < 2; ++ti) {
            const f32x4 a = ti ? acc1 : acc0;
            const float gi = fast_sigmoid(a[0]);
            const float gf = fast_sigmoid(a[1]);
            const float gg = fast_tanh(a[2]);
            const float go = fast_sigmoid(a[3]);
            c[ti] = gf * c[ti] + gi * gg;
            const float h = go * fast_tanh(c[ti]);
            hr[ti] = h;
            const int u = 4 * (w + 8 * ti) + lg;
            if (u < HID) buf[p ^ 1][lr][u] = f2bf(h);
        }
        __syncthreads();
    }

    // ---- FC epilogue: out[b] = sum_u W_fc[u]*h_T[u][b] + b_fc ----
    float partial = wfc[0] * hr[0] + wfc[1] * hr[1];   // wfc==0 for pad units
    partial += __shfl_down(partial, 32);
    partial += __shfl_down(partial, 16);
    if (l < 16) atomicAdd(&red[l], partial);
    __syncthreads();
    if (tid < BT) out[b0 + tid] = red[tid] + b_fc[0];
}

extern "C" void kernel_launch(void* const* d_in, const int* in_sizes, int n_in,
                              void* d_out, int out_size, void* d_ws, size_t ws_size,
                              hipStream_t stream) {
    const float* x    = (const float*)d_in[0];
    const float* W_ih = (const float*)d_in[1];
    const float* W_hh = (const float*)d_in[2];
    const float* b_ih = (const float*)d_in[3];
    const float* b_hh = (const float*)d_in[4];
    const float* W_fc = (const float*)d_in[5];
    const float* b_fc = (const float*)d_in[6];
    float* out        = (float*)d_out;

    const int B = in_sizes[0] / (TT * NIN);   // 4096
    lstm_mfma<<<B / BT, 64 * NW, 0, stream>>>(x, W_ih, W_hh, b_ih, b_hh, W_fc, b_fc, out);
}